// Round 1
// baseline (979.209 us; speedup 1.0000x reference)
//
#include <hip/hip_runtime.h>
#include <math.h>

// ---------------------------------------------------------------------------
// TemporalGNN: 2-layer GCN over 200k nodes / 640k edges + self-loops,
// then 65536-row gather + 3-layer MLP + sigmoid.
// All fp32. Layout decisions:
//   ws: [deg/dinv: 262144 f] [Ha/Hb: N*128 f] [agg1/agg2: N*128 f]
//       [flags: 2048 i] [numUsers: 1 i]
//   - self-loop message + bias fused into GEMM epilogue (agg_init = b + h*dinv^2)
//   - GEMM2 reads relu(agg1) and writes agg2 IN PLACE over agg1 (row-local)
//   - edge aggregation: one wave per edge, 2 fp32 atomics/lane (coalesced)
// ---------------------------------------------------------------------------

#define HDIM 128

__global__ __launch_bounds__(256) void init_kernel(float* __restrict__ deg,
                                                   int* __restrict__ flags, int n) {
    int i = blockIdx.x * 256 + threadIdx.x;
    if (i < n) deg[i] = 1.0f;           // self-loop contributes 1 to every degree
    if (i < 2048) flags[i] = 0;
}

__global__ __launch_bounds__(256) void deg_kernel(const int* __restrict__ dst,
                                                  float* __restrict__ deg, int e) {
    int i = blockIdx.x * 256 + threadIdx.x;
    int stride = gridDim.x * 256;
    for (; i < e; i += stride) atomicAdd(&deg[dst[i]], 1.0f);
}

__global__ __launch_bounds__(256) void dinv_kernel(float* __restrict__ deg, int n) {
    int i = blockIdx.x * 256 + threadIdx.x;
    if (i < n) deg[i] = rsqrtf(deg[i]);  // deg >= 1 always (self-loops)
}

// GEMM: Hout[row] = X[row] @ W  (X: n x K, W: K x 128)
// epilogue: aggOut[row] = bias + Hout[row] * dinv[row]^2   (self-loop + bias init)
// RELU_IN: apply relu to X on read (conv2 consumes relu(conv1_out)).
// NOTE: X and aggOut may alias (in-place conv2): row read fully into LDS before write.
template <int K, bool RELU_IN>
__global__ __launch_bounds__(256) void gcn_gemm(const float* X,
                                                const float* __restrict__ W,
                                                const float* __restrict__ bias,
                                                const float* __restrict__ dinv,
                                                float* __restrict__ Hout,
                                                float* aggOut, int n) {
    __shared__ float wl[64 * 128];       // 32 KB: one 64-row chunk of W
    __shared__ float xl[32][K];          // 8 KB (K=64) / 16 KB (K=128)

    const int tid = threadIdx.x;
    const int lane = tid & 63;
    const int wid = tid >> 6;            // 4 waves, 8 rows each
    const float bj0 = bias[lane];
    const float bj1 = bias[lane + 64];

    const int rowBase = blockIdx.x * 32;

    // stage 32 rows of X
    for (int idx = tid; idx < 32 * K; idx += 256) {
        int r = (K == 64) ? (idx >> 6) : (idx >> 7);
        int c = idx & (K - 1);
        int row = rowBase + r;
        float v = (row < n) ? X[(size_t)row * K + c] : 0.f;
        if (RELU_IN) v = fmaxf(v, 0.f);
        xl[r][c] = v;
    }

    float acc[8][2] = {};
    for (int chunk = 0; chunk < K / 64; ++chunk) {
        __syncthreads();   // xl staged / previous wl consumed
        for (int idx = tid; idx < 64 * 128; idx += 256)
            wl[idx] = W[chunk * 64 * 128 + idx];
        __syncthreads();
        for (int k2 = 0; k2 < 64; k2 += 4) {
            float w[4][2];
#pragma unroll
            for (int u = 0; u < 4; ++u) {
                w[u][0] = wl[(k2 + u) * 128 + lane];
                w[u][1] = wl[(k2 + u) * 128 + 64 + lane];
            }
#pragma unroll
            for (int r = 0; r < 8; ++r) {
                const float4 x4 = *(const float4*)&xl[wid * 8 + r][chunk * 64 + k2];
                acc[r][0] = fmaf(x4.x, w[0][0], acc[r][0]);
                acc[r][1] = fmaf(x4.x, w[0][1], acc[r][1]);
                acc[r][0] = fmaf(x4.y, w[1][0], acc[r][0]);
                acc[r][1] = fmaf(x4.y, w[1][1], acc[r][1]);
                acc[r][0] = fmaf(x4.z, w[2][0], acc[r][0]);
                acc[r][1] = fmaf(x4.z, w[2][1], acc[r][1]);
                acc[r][0] = fmaf(x4.w, w[3][0], acc[r][0]);
                acc[r][1] = fmaf(x4.w, w[3][1], acc[r][1]);
            }
        }
    }

#pragma unroll
    for (int r = 0; r < 8; ++r) {
        int row = rowBase + wid * 8 + r;
        if (row < n) {
            float di = dinv[row];
            float sl = di * di;
            float h0 = acc[r][0], h1 = acc[r][1];
            Hout[(size_t)row * HDIM + lane] = h0;
            Hout[(size_t)row * HDIM + 64 + lane] = h1;
            aggOut[(size_t)row * HDIM + lane] = fmaf(h0, sl, bj0);
            aggOut[(size_t)row * HDIM + 64 + lane] = fmaf(h1, sl, bj1);
        }
    }
}

// one wave per edge: agg[dst] += H[src] * dinv[src]*dinv[dst]
__global__ __launch_bounds__(256) void scatter_kernel(const int* __restrict__ src,
                                                      const int* __restrict__ dst,
                                                      const float* __restrict__ dinv,
                                                      const float* __restrict__ Hrow,
                                                      float* __restrict__ agg, int e) {
    const int lane = threadIdx.x & 63;
    int gw = (blockIdx.x * 256 + threadIdx.x) >> 6;
    const int nw = (gridDim.x * 256) >> 6;
    for (int ed = gw; ed < e; ed += nw) {
        int s = src[ed], d = dst[ed];
        float w = dinv[s] * dinv[d];
        float v0 = Hrow[(size_t)s * HDIM + lane] * w;
        float v1 = Hrow[(size_t)s * HDIM + 64 + lane] * w;
        atomicAdd(&agg[(size_t)d * HDIM + lane], v0);
        atomicAdd(&agg[(size_t)d * HDIM + 64 + lane], v1);
    }
}

__global__ __launch_bounds__(256) void mark_kernel(const int* __restrict__ items,
                                                   int* __restrict__ flags, int b) {
    int i = blockIdx.x * 256 + threadIdx.x;
    if (i < b) flags[items[i]] = 1;
}

__global__ __launch_bounds__(256) void count_kernel(const int* __restrict__ flags,
                                                    int* __restrict__ numUsers, int n) {
    __shared__ int sred[4];
    int tid = threadIdx.x;
    int s = 0;
    for (int i = tid; i < 2048; i += 256) s += flags[i];
    for (int m = 32; m; m >>= 1) s += __shfl_xor(s, m, 64);
    if ((tid & 63) == 0) sred[tid >> 6] = s;
    __syncthreads();
    if (tid == 0) *numUsers = n - (sred[0] + sred[1] + sred[2] + sred[3]);
}

#define MLP_ROWS 8
__global__ __launch_bounds__(256) void mlp_kernel(
    const float* __restrict__ h, const int* __restrict__ users,
    const int* __restrict__ items, const int* __restrict__ numUsersPtr,
    const float* __restrict__ fc1w, const float* __restrict__ fc1b,
    const float* __restrict__ fc2w, const float* __restrict__ fc2b,
    const float* __restrict__ outw, const float* __restrict__ outb,
    float* __restrict__ out, int bsize) {
    __shared__ float zl[4][MLP_ROWS][256];  // 32 KB
    __shared__ float a1l[4][MLP_ROWS][64];  // 8 KB

    const int tid = threadIdx.x;
    const int lane = tid & 63;
    const int wid = tid >> 6;
    const int nu = *numUsersPtr;
    const int wavesTotal = (gridDim.x * 256) >> 6;
    const int gw = (blockIdx.x * 256 + tid) >> 6;
    const float f1b = fc1b[lane];
    const float ob = outb[0];

    for (int base = gw * MLP_ROWS; base < bsize; base += wavesTotal * MLP_ROWS) {
        // gather z = [user_emb(128) | item_emb(128)]
#pragma unroll
        for (int r = 0; r < MLP_ROWS; ++r) {
            int row = base + r;
            if (row < bsize) {
                int u = users[row];
                int it = nu + items[row];
                zl[wid][r][lane] = h[(size_t)u * HDIM + lane];
                zl[wid][r][lane + 64] = h[(size_t)u * HDIM + 64 + lane];
                zl[wid][r][128 + lane] = h[(size_t)it * HDIM + lane];
                zl[wid][r][192 + lane] = h[(size_t)it * HDIM + 64 + lane];
            }
        }
        // fc1: out col = lane (64 outputs), 8 rows per wave
        float acc[MLP_ROWS];
#pragma unroll
        for (int r = 0; r < MLP_ROWS; ++r) acc[r] = f1b;
        for (int k = 0; k < 256; k += 4) {
            float w0 = fc1w[k * 64 + lane];
            float w1 = fc1w[(k + 1) * 64 + lane];
            float w2 = fc1w[(k + 2) * 64 + lane];
            float w3 = fc1w[(k + 3) * 64 + lane];
#pragma unroll
            for (int r = 0; r < MLP_ROWS; ++r) {
                const float4 z4 = *(const float4*)&zl[wid][r][k];
                acc[r] = fmaf(z4.x, w0, acc[r]);
                acc[r] = fmaf(z4.y, w1, acc[r]);
                acc[r] = fmaf(z4.z, w2, acc[r]);
                acc[r] = fmaf(z4.w, w3, acc[r]);
            }
        }
#pragma unroll
        for (int r = 0; r < MLP_ROWS; ++r) a1l[wid][r][lane] = fmaxf(acc[r], 0.f);

        // fc2 (64->32) + out (32->1): two rows at a time (lane halves)
        const int half = lane >> 5, j = lane & 31;
        for (int rp = 0; rp < MLP_ROWS; rp += 2) {
            int r = rp + half;
            float acc2 = fc2b[j];
#pragma unroll
            for (int o = 0; o < 64; ++o)
                acc2 = fmaf(a1l[wid][r][o], fc2w[o * 32 + j], acc2);
            float p = fmaxf(acc2, 0.f) * outw[j];
            for (int m = 16; m; m >>= 1) p += __shfl_xor(p, m, 32);
            if (j == 0) {
                int row = base + r;
                if (row < bsize) out[row] = 1.f / (1.f + expf(-(p + ob)));
            }
        }
    }
}

extern "C" void kernel_launch(void* const* d_in, const int* in_sizes, int n_in,
                              void* d_out, int out_size, void* d_ws, size_t ws_size,
                              hipStream_t stream) {
    const float* x = (const float*)d_in[0];
    const float* W1 = (const float*)d_in[1];
    const float* b1 = (const float*)d_in[2];
    const float* W2 = (const float*)d_in[3];
    const float* b2 = (const float*)d_in[4];
    const float* fc1w = (const float*)d_in[5];
    const float* fc1b = (const float*)d_in[6];
    const float* fc2w = (const float*)d_in[7];
    const float* fc2b = (const float*)d_in[8];
    const float* outw = (const float*)d_in[9];
    const float* outb = (const float*)d_in[10];
    const int* ei = (const int*)d_in[11];
    const int* users = (const int*)d_in[12];
    const int* items = (const int*)d_in[13];

    const int n = in_sizes[0] / 64;   // 200000 nodes
    const int e = in_sizes[11] / 2;   // 640000 edges
    const int b = in_sizes[12];       // 65536 batch

    const int* srcp = ei;
    const int* dstp = ei + e;

    float* f = (float*)d_ws;
    float* deg = f;                             // N (becomes dinv in-place)
    float* Ha = f + (1 << 18);                  // N*128 (h1, then h2)
    float* agg = Ha + (size_t)n * HDIM;         // N*128 (agg1, then agg2 in-place)
    int* flags = (int*)(agg + (size_t)n * HDIM);
    int* numUsers = flags + 2048;

    const int nb_n = (n + 255) / 256;
    const int nb_rows = (n + 31) / 32;

    hipLaunchKernelGGL(init_kernel, dim3(nb_n), dim3(256), 0, stream, deg, flags, n);
    hipLaunchKernelGGL(deg_kernel, dim3(2500), dim3(256), 0, stream, dstp, deg, e);
    hipLaunchKernelGGL(dinv_kernel, dim3(nb_n), dim3(256), 0, stream, deg, n);

    // conv1: h1 = x@W1; agg1 = b1 + h1*dinv^2; += edge messages
    hipLaunchKernelGGL((gcn_gemm<64, false>), dim3(nb_rows), dim3(256), 0, stream,
                       x, W1, b1, deg, Ha, agg, n);
    hipLaunchKernelGGL(scatter_kernel, dim3(20000), dim3(256), 0, stream,
                       srcp, dstp, deg, Ha, agg, e);

    // conv2: h2 = relu(agg1)@W2; agg2 = b2 + h2*dinv^2 (in place); += edges
    hipLaunchKernelGGL((gcn_gemm<128, true>), dim3(nb_rows), dim3(256), 0, stream,
                       agg, W2, b2, deg, Ha, agg, n);
    hipLaunchKernelGGL(scatter_kernel, dim3(20000), dim3(256), 0, stream,
                       srcp, dstp, deg, Ha, agg, e);

    // num_users = n - |unique(items)|
    hipLaunchKernelGGL(mark_kernel, dim3((b + 255) / 256), dim3(256), 0, stream,
                       items, flags, b);
    hipLaunchKernelGGL(count_kernel, dim3(1), dim3(256), 0, stream, flags, numUsers, n);

    // gather + MLP + sigmoid
    hipLaunchKernelGGL(mlp_kernel, dim3(2048), dim3(256), 0, stream,
                       agg, users, items, numUsers, fc1w, fc1b, fc2w, fc2b,
                       outw, outb, (float*)d_out, b);
}

// Round 2
// 637.041 us; speedup vs baseline: 1.5371x; 1.5371x over previous
//
#include <hip/hip_runtime.h>
#include <math.h>

// ---------------------------------------------------------------------------
// TemporalGNN round 2: atomic scatter (2x259us, WRITE_SIZE=320MB of atomic
// RMW write-through) replaced by on-device CSR build + gather-side
// aggregation (agg written once, 102MB). Self-loop+bias+relu folded into
// gather epilogue; GEMMs write H only.
// ---------------------------------------------------------------------------

#define HDIM 128

__global__ __launch_bounds__(256) void init_kernel(int* __restrict__ cnt,
                                                   int* __restrict__ flags,
                                                   int* __restrict__ off, int n, int e) {
    int i = blockIdx.x * 256 + threadIdx.x;
    if (i < n) cnt[i] = 0;
    if (i < 2048) flags[i] = 0;
    if (i == 0) off[n] = e;   // scan_final writes off[0..n-1] only
}

__global__ __launch_bounds__(256) void hist_kernel(const int* __restrict__ dst,
                                                   int* __restrict__ cnt, int e) {
    int i = blockIdx.x * 256 + threadIdx.x;
    int stride = gridDim.x * 256;
    for (; i < e; i += stride) atomicAdd(&cnt[dst[i]], 1);
}

__global__ __launch_bounds__(256) void dinv_kernel(const int* __restrict__ cnt,
                                                   float* __restrict__ dinv, int n) {
    int i = blockIdx.x * 256 + threadIdx.x;
    if (i < n) dinv[i] = rsqrtf((float)cnt[i] + 1.0f);  // +1 = self-loop
}

// ---- exclusive scan over cnt[0..n) -> off, cursor (1024 elems per block) ----
__global__ __launch_bounds__(256) void scan_blocksums(const int* __restrict__ cnt,
                                                      int* __restrict__ bsums, int n) {
    int base = blockIdx.x * 1024, t = threadIdx.x;
    int s = 0;
#pragma unroll
    for (int j = 0; j < 4; ++j) { int i = base + t * 4 + j; if (i < n) s += cnt[i]; }
    __shared__ int red[256];
    red[t] = s; __syncthreads();
    for (int o = 128; o; o >>= 1) { if (t < o) red[t] += red[t + o]; __syncthreads(); }
    if (t == 0) bsums[blockIdx.x] = red[0];
}

__global__ __launch_bounds__(256) void scan_top(int* __restrict__ bsums, int nb) {
    __shared__ int sh[256];
    int t = threadIdx.x;
    int v = (t < nb) ? bsums[t] : 0;
    sh[t] = v; __syncthreads();
    for (int o = 1; o < 256; o <<= 1) {
        int u = (t >= o) ? sh[t - o] : 0;
        __syncthreads();
        sh[t] += u;
        __syncthreads();
    }
    if (t < nb) bsums[t] = sh[t] - v;  // exclusive
}

// cursor may alias cnt: each index is read then written by the same thread only.
__global__ __launch_bounds__(256) void scan_final(const int* __restrict__ cnt,
                                                  const int* __restrict__ bsums,
                                                  int* __restrict__ off,
                                                  int* cursor, int n) {
    int base = blockIdx.x * 1024, t = threadIdx.x;
    int v[4]; int s = 0;
#pragma unroll
    for (int j = 0; j < 4; ++j) { int i = base + t * 4 + j; v[j] = (i < n) ? cnt[i] : 0; s += v[j]; }
    __shared__ int sh[256];
    sh[t] = s; __syncthreads();
    for (int o = 1; o < 256; o <<= 1) {
        int u = (t >= o) ? sh[t - o] : 0;
        __syncthreads();
        sh[t] += u;
        __syncthreads();
    }
    int p = bsums[blockIdx.x] + (sh[t] - s);
#pragma unroll
    for (int j = 0; j < 4; ++j) {
        int i = base + t * 4 + j;
        if (i < n) { off[i] = p; cursor[i] = p; p += v[j]; }
    }
}

__global__ __launch_bounds__(256) void build_csr(const int* __restrict__ src,
                                                 const int* __restrict__ dst,
                                                 const float* __restrict__ dinv,
                                                 int* __restrict__ cursor,
                                                 int* __restrict__ csr_src,
                                                 float* __restrict__ csr_w, int e) {
    int i = blockIdx.x * 256 + threadIdx.x;
    int stride = gridDim.x * 256;
    for (; i < e; i += stride) {
        int s = src[i], d = dst[i];
        int p = atomicAdd(&cursor[d], 1);
        csr_src[p] = s;
        csr_w[p] = dinv[s] * dinv[d];
    }
}

// ---- GEMM: Hout = X @ W (X: n x K, W: K x 128). No epilogue. ----
template <int K>
__global__ __launch_bounds__(256) void gcn_gemm(const float* __restrict__ X,
                                                const float* __restrict__ W,
                                                float* __restrict__ Hout, int n) {
    __shared__ float wl[64 * 128];   // 32 KB
    __shared__ float xl[32][K];

    const int tid = threadIdx.x;
    const int lane = tid & 63;
    const int wid = tid >> 6;
    const int rowBase = blockIdx.x * 32;

    for (int idx = tid; idx < 32 * K; idx += 256) {
        int r = (K == 64) ? (idx >> 6) : (idx >> 7);
        int c = idx & (K - 1);
        int row = rowBase + r;
        xl[r][c] = (row < n) ? X[(size_t)row * K + c] : 0.f;
    }

    float acc[8][2] = {};
    for (int chunk = 0; chunk < K / 64; ++chunk) {
        __syncthreads();
        for (int idx = tid; idx < 64 * 128; idx += 256)
            wl[idx] = W[chunk * 64 * 128 + idx];
        __syncthreads();
        for (int k2 = 0; k2 < 64; k2 += 4) {
            float w[4][2];
#pragma unroll
            for (int u = 0; u < 4; ++u) {
                w[u][0] = wl[(k2 + u) * 128 + lane];
                w[u][1] = wl[(k2 + u) * 128 + 64 + lane];
            }
#pragma unroll
            for (int r = 0; r < 8; ++r) {
                const float4 x4 = *(const float4*)&xl[wid * 8 + r][chunk * 64 + k2];
                acc[r][0] = fmaf(x4.x, w[0][0], acc[r][0]);
                acc[r][1] = fmaf(x4.x, w[0][1], acc[r][1]);
                acc[r][0] = fmaf(x4.y, w[1][0], acc[r][0]);
                acc[r][1] = fmaf(x4.y, w[1][1], acc[r][1]);
                acc[r][0] = fmaf(x4.z, w[2][0], acc[r][0]);
                acc[r][1] = fmaf(x4.z, w[2][1], acc[r][1]);
                acc[r][0] = fmaf(x4.w, w[3][0], acc[r][0]);
                acc[r][1] = fmaf(x4.w, w[3][1], acc[r][1]);
            }
        }
    }

#pragma unroll
    for (int r = 0; r < 8; ++r) {
        int row = rowBase + wid * 8 + r;
        if (row < n) {
            Hout[(size_t)row * HDIM + lane] = acc[r][0];
            Hout[(size_t)row * HDIM + 64 + lane] = acc[r][1];
        }
    }
}

// ---- gather-side aggregation: one wave per dst node ----
// agg[d] = bias + H[d]*dinv[d]^2 + sum_{in-edges} H[src]*w ; optional relu.
template <bool RELU>
__global__ __launch_bounds__(256) void gather_agg(const int* __restrict__ off,
                                                  const int* __restrict__ csr_src,
                                                  const float* __restrict__ csr_w,
                                                  const float* __restrict__ dinv,
                                                  const float* __restrict__ H,
                                                  const float* __restrict__ bias,
                                                  float* __restrict__ agg, int n) {
    const int lane = threadIdx.x & 63;
    const int d = blockIdx.x * 4 + (threadIdx.x >> 6);
    if (d >= n) return;

    float di = dinv[d];
    float sl = di * di;
    float a0 = fmaf(H[(size_t)d * HDIM + lane], sl, bias[lane]);
    float a1 = fmaf(H[(size_t)d * HDIM + 64 + lane], sl, bias[64 + lane]);

    int p0 = off[d], p1 = off[d + 1];
    for (int p = p0; p < p1; ++p) {
        int s = csr_src[p];
        float w = csr_w[p];
        a0 = fmaf(H[(size_t)s * HDIM + lane], w, a0);
        a1 = fmaf(H[(size_t)s * HDIM + 64 + lane], w, a1);
    }
    if (RELU) { a0 = fmaxf(a0, 0.f); a1 = fmaxf(a1, 0.f); }
    agg[(size_t)d * HDIM + lane] = a0;
    agg[(size_t)d * HDIM + 64 + lane] = a1;
}

__global__ __launch_bounds__(256) void mark_kernel(const int* __restrict__ items,
                                                   int* __restrict__ flags, int b) {
    int i = blockIdx.x * 256 + threadIdx.x;
    if (i < b) flags[items[i]] = 1;
}

__global__ __launch_bounds__(256) void count_kernel(const int* __restrict__ flags,
                                                    int* __restrict__ numUsers, int n) {
    __shared__ int sred[4];
    int tid = threadIdx.x;
    int s = 0;
    for (int i = tid; i < 2048; i += 256) s += flags[i];
    for (int m = 32; m; m >>= 1) s += __shfl_xor(s, m, 64);
    if ((tid & 63) == 0) sred[tid >> 6] = s;
    __syncthreads();
    if (tid == 0) *numUsers = n - (sred[0] + sred[1] + sred[2] + sred[3]);
}

#define MLP_ROWS 8
__global__ __launch_bounds__(256) void mlp_kernel(
    const float* __restrict__ h, const int* __restrict__ users,
    const int* __restrict__ items, const int* __restrict__ numUsersPtr,
    const float* __restrict__ fc1w, const float* __restrict__ fc1b,
    const float* __restrict__ fc2w, const float* __restrict__ fc2b,
    const float* __restrict__ outw, const float* __restrict__ outb,
    float* __restrict__ out, int bsize) {
    __shared__ float zl[4][MLP_ROWS][256];
    __shared__ float a1l[4][MLP_ROWS][64];

    const int tid = threadIdx.x;
    const int lane = tid & 63;
    const int wid = tid >> 6;
    const int nu = *numUsersPtr;
    const int wavesTotal = (gridDim.x * 256) >> 6;
    const int gw = (blockIdx.x * 256 + tid) >> 6;
    const float f1b = fc1b[lane];
    const float ob = outb[0];

    for (int base = gw * MLP_ROWS; base < bsize; base += wavesTotal * MLP_ROWS) {
#pragma unroll
        for (int r = 0; r < MLP_ROWS; ++r) {
            int row = base + r;
            if (row < bsize) {
                int u = users[row];
                int it = nu + items[row];
                zl[wid][r][lane] = h[(size_t)u * HDIM + lane];
                zl[wid][r][lane + 64] = h[(size_t)u * HDIM + 64 + lane];
                zl[wid][r][128 + lane] = h[(size_t)it * HDIM + lane];
                zl[wid][r][192 + lane] = h[(size_t)it * HDIM + 64 + lane];
            }
        }
        float acc[MLP_ROWS];
#pragma unroll
        for (int r = 0; r < MLP_ROWS; ++r) acc[r] = f1b;
        for (int k = 0; k < 256; k += 4) {
            float w0 = fc1w[k * 64 + lane];
            float w1 = fc1w[(k + 1) * 64 + lane];
            float w2 = fc1w[(k + 2) * 64 + lane];
            float w3 = fc1w[(k + 3) * 64 + lane];
#pragma unroll
            for (int r = 0; r < MLP_ROWS; ++r) {
                const float4 z4 = *(const float4*)&zl[wid][r][k];
                acc[r] = fmaf(z4.x, w0, acc[r]);
                acc[r] = fmaf(z4.y, w1, acc[r]);
                acc[r] = fmaf(z4.z, w2, acc[r]);
                acc[r] = fmaf(z4.w, w3, acc[r]);
            }
        }
#pragma unroll
        for (int r = 0; r < MLP_ROWS; ++r) a1l[wid][r][lane] = fmaxf(acc[r], 0.f);

        const int half = lane >> 5, j = lane & 31;
        for (int rp = 0; rp < MLP_ROWS; rp += 2) {
            int r = rp + half;
            float acc2 = fc2b[j];
#pragma unroll
            for (int o = 0; o < 64; ++o)
                acc2 = fmaf(a1l[wid][r][o], fc2w[o * 32 + j], acc2);
            float p = fmaxf(acc2, 0.f) * outw[j];
            for (int m = 16; m; m >>= 1) p += __shfl_xor(p, m, 32);
            if (j == 0) {
                int row = base + r;
                if (row < bsize) out[row] = 1.f / (1.f + expf(-(p + ob)));
            }
        }
    }
}

extern "C" void kernel_launch(void* const* d_in, const int* in_sizes, int n_in,
                              void* d_out, int out_size, void* d_ws, size_t ws_size,
                              hipStream_t stream) {
    const float* x = (const float*)d_in[0];
    const float* W1 = (const float*)d_in[1];
    const float* b1 = (const float*)d_in[2];
    const float* W2 = (const float*)d_in[3];
    const float* b2 = (const float*)d_in[4];
    const float* fc1w = (const float*)d_in[5];
    const float* fc1b = (const float*)d_in[6];
    const float* fc2w = (const float*)d_in[7];
    const float* fc2b = (const float*)d_in[8];
    const float* outw = (const float*)d_in[9];
    const float* outb = (const float*)d_in[10];
    const int* ei = (const int*)d_in[11];
    const int* users = (const int*)d_in[12];
    const int* items = (const int*)d_in[13];

    const int n = in_sizes[0] / 64;   // 200000
    const int e = in_sizes[11] / 2;   // 640000
    const int b = in_sizes[12];       // 65536

    const int* srcp = ei;
    const int* dstp = ei + e;

    // ---- workspace bump allocator (256B aligned) ----
    char* wp = (char*)d_ws;
    auto alloc = [&](size_t bytes) { char* r = wp; wp += (bytes + 255) & ~(size_t)255; return r; };
    float* dinv   = (float*)alloc((size_t)n * 4);
    int*   cnt    = (int*)alloc((size_t)n * 4);       // becomes cursor in-place
    int*   off    = (int*)alloc((size_t)(n + 1) * 4);
    int*   bsums  = (int*)alloc(1024);
    int*   csrs   = (int*)alloc((size_t)e * 4);
    float* csrw   = (float*)alloc((size_t)e * 4);
    int*   flags  = (int*)alloc(2048 * 4);
    int*   numUsers = (int*)alloc(256);
    float* Ha     = (float*)alloc((size_t)n * HDIM * 4);
    float* agg    = (float*)alloc((size_t)n * HDIM * 4);

    const int nb_n = (n + 255) / 256;        // 782
    const int nb_scan = (n + 1023) / 1024;   // 196
    const int nb_rows = (n + 31) / 32;       // 6250
    const int nb_gather = (n + 3) / 4;       // 50000

    hipLaunchKernelGGL(init_kernel, dim3(nb_n), dim3(256), 0, stream, cnt, flags, off, n, e);
    hipLaunchKernelGGL(hist_kernel, dim3(2500), dim3(256), 0, stream, dstp, cnt, e);
    hipLaunchKernelGGL(dinv_kernel, dim3(nb_n), dim3(256), 0, stream, cnt, dinv, n);
    hipLaunchKernelGGL(scan_blocksums, dim3(nb_scan), dim3(256), 0, stream, cnt, bsums, n);
    hipLaunchKernelGGL(scan_top, dim3(1), dim3(256), 0, stream, bsums, nb_scan);
    hipLaunchKernelGGL(scan_final, dim3(nb_scan), dim3(256), 0, stream, cnt, bsums, off, cnt, n);
    hipLaunchKernelGGL(build_csr, dim3(2500), dim3(256), 0, stream,
                       srcp, dstp, dinv, cnt, csrs, csrw, e);

    // conv1: h1 = x@W1 ; agg1 = relu(b1 + selfloop + edges)
    hipLaunchKernelGGL((gcn_gemm<64>), dim3(nb_rows), dim3(256), 0, stream, x, W1, Ha, n);
    hipLaunchKernelGGL((gather_agg<true>), dim3(nb_gather), dim3(256), 0, stream,
                       off, csrs, csrw, dinv, Ha, b1, agg, n);

    // conv2: h2 = agg1@W2 ; agg2 = b2 + selfloop + edges (no relu)
    hipLaunchKernelGGL((gcn_gemm<128>), dim3(nb_rows), dim3(256), 0, stream, agg, W2, Ha, n);
    hipLaunchKernelGGL((gather_agg<false>), dim3(nb_gather), dim3(256), 0, stream,
                       off, csrs, csrw, dinv, Ha, b2, agg, n);

    // num_users = n - |unique(items)|
    hipLaunchKernelGGL(mark_kernel, dim3((b + 255) / 256), dim3(256), 0, stream, items, flags, b);
    hipLaunchKernelGGL(count_kernel, dim3(1), dim3(256), 0, stream, flags, numUsers, n);

    hipLaunchKernelGGL(mlp_kernel, dim3(2048), dim3(256), 0, stream,
                       agg, users, items, numUsers, fc1w, fc1b, fc2w, fc2b,
                       outw, outb, (float*)d_out, b);
}